// Round 19
// baseline (145.493 us; speedup 1.0000x reference)
//
#include <hip/hip_runtime.h>
#include <math.h>

typedef __bf16 bf16;
typedef __bf16 bf16x8 __attribute__((ext_vector_type(8)));
typedef __bf16 bf16x4 __attribute__((ext_vector_type(4)));
typedef __bf16 bf16x2 __attribute__((ext_vector_type(2)));
typedef float f32x4 __attribute__((ext_vector_type(4)));
typedef float f32x2 __attribute__((ext_vector_type(2)));
typedef float f32x16 __attribute__((ext_vector_type(16)));
typedef unsigned int u32;
typedef unsigned int u32x4 __attribute__((ext_vector_type(4)));

#define AS1 __attribute__((address_space(1)))
#define AS3 __attribute__((address_space(3)))

static __device__ __forceinline__ f32x4 mfma16(bf16x8 a, bf16x8 b, f32x4 c) {
    return __builtin_amdgcn_mfma_f32_16x16x32_bf16(a, b, c, 0, 0, 0);
}
static __device__ __forceinline__ f32x16 mfma32(bf16x8 a, bf16x8 b, f32x16 c) {
    return __builtin_amdgcn_mfma_f32_32x32x16_bf16(a, b, c, 0, 0, 0);
}
static __device__ __forceinline__ u32 pk2(float a, float b) {
    bf16x2 v; v[0] = (bf16)a; v[1] = (bf16)b;
    return __builtin_bit_cast(u32, v);
}
// fast GELU (tanh form): max |err| vs exact-erf gelu ~5e-4.
static __device__ __forceinline__ float gelu_f(float x) {
    float u = 0.7978845608f * x * __builtin_fmaf(0.044715f, x * x, 1.0f);
    float e = __expf(2.0f * u);
    return x - x * __builtin_amdgcn_rcpf(e + 1.0f);
}

// ---------------------------------------------------------------------------
// Convert the six weight matrices f32 -> bf16 into one packed ws region.
// ---------------------------------------------------------------------------
__global__ __launch_bounds__(256) void cvt_w6(
    const float* __restrict__ s0, const float* __restrict__ s1,
    const float* __restrict__ s2, const float* __restrict__ s3,
    const float* __restrict__ s4, const float* __restrict__ s5,
    bf16* __restrict__ dst)
{
    int i = (blockIdx.x * 256 + threadIdx.x) * 4;
    const float* src; int off;
    if      (i <  49152) { src = s0; off = 0; }
    else if (i <  65536) { src = s1; off = 49152; }
    else if (i < 114688) { src = s2; off = 65536; }
    else if (i < 131072) { src = s3; off = 114688; }
    else if (i < 196608) { src = s4; off = 131072; }
    else                 { src = s5; off = 196608; }
    f32x4 v = *(const f32x4*)&src[i - off];
    bf16x4 b;
    b[0] = (bf16)v[0]; b[1] = (bf16)v[1]; b[2] = (bf16)v[2]; b[3] = (bf16)v[3];
    *(bf16x4*)&dst[i] = b;
}

// ---------------------------------------------------------------------------
// Row-wave GEMM (r13 version): out[M, NT*128] = epi(A @ W^T + bias (+res))
// Block = 64 rows, 4 waves; each wave owns 16 FULL rows. NT column tiles
// looped in-kernel so A (and the fused input-LN) is read/computed once.
// ---------------------------------------------------------------------------
template<int OUT_BF16, int RES, int RESBF, int GELU_, int LNA, int RMAP, int KT, int NT>
__global__ __launch_bounds__(256) void gemm_rw(
    const bf16* __restrict__ A, const bf16* __restrict__ W,
    const float* __restrict__ bias, const void* __restrict__ res,
    void* __restrict__ outp,
    const float* __restrict__ xf, const float* __restrict__ lnaw,
    const float* __restrict__ lnab)
{
    constexpr int N = NT * 128;
    __shared__ __align__(16) bf16 Bs[128 * 64];
    const int tid  = threadIdx.x;
    const int lane = tid & 63;
    const int w    = tid >> 6;
    const int li = lane & 15, g = lane >> 4;
    const int m0 = blockIdx.x * 64;
    const int arow = m0 + w * 16 + li;
    int srow = arow;
    if constexpr (RMAP) {
        int b = arow >> 15, t = (arow >> 7) & 255, f = arow & 127;
        srow = (b << 15) + (f << 8) + t;
    }
    const bf16* ap = A + (size_t)srow * KT;

    bf16x8 afrag[4];
    if constexpr (LNA) {
        // arow is in [B,F,T] order; source x row is [B,T,F]
        int b = arow >> 15, f = (arow >> 8) & 127, t = arow & 255;
        const float* xp = xf + (((size_t)b * 256 + t) * 128 + f) * 128;
        f32x4 cv[8];
        #pragma unroll
        for (int cc = 0; cc < 4; ++cc) {
            cv[2 * cc]     = *(const f32x4*)&xp[cc * 32 + g * 8];
            cv[2 * cc + 1] = *(const f32x4*)&xp[cc * 32 + g * 8 + 4];
        }
        float sm = 0.f, sq = 0.f;
        #pragma unroll
        for (int i = 0; i < 8; ++i)
            #pragma unroll
            for (int j = 0; j < 4; ++j) { float v = cv[i][j]; sm += v; sq += v * v; }
        sm += __shfl_xor(sm, 16); sm += __shfl_xor(sm, 32);
        sq += __shfl_xor(sq, 16); sq += __shfl_xor(sq, 32);
        float mu = sm * 0.0078125f;
        float rs = rsqrtf(sq * 0.0078125f - mu * mu + 1e-5f);
        #pragma unroll
        for (int cc = 0; cc < 4; ++cc) {
            f32x4 w0 = *(const f32x4*)&lnaw[cc * 32 + g * 8];
            f32x4 w1 = *(const f32x4*)&lnaw[cc * 32 + g * 8 + 4];
            f32x4 b0 = *(const f32x4*)&lnab[cc * 32 + g * 8];
            f32x4 b1 = *(const f32x4*)&lnab[cc * 32 + g * 8 + 4];
            #pragma unroll
            for (int j = 0; j < 4; ++j) {
                afrag[cc][j]     = (bf16)((cv[2 * cc][j]     - mu) * rs * w0[j] + b0[j]);
                afrag[cc][4 + j] = (bf16)((cv[2 * cc + 1][j] - mu) * rs * w1[j] + b1[j]);
            }
        }
    } else if constexpr (KT == 128) {
        #pragma unroll
        for (int cc = 0; cc < 4; ++cc)
            afrag[cc] = *(const bf16x8*)&ap[cc * 32 + g * 8];
    }

    #pragma unroll
    for (int t = 0; t < NT; ++t) {
        const int n0 = t * 128;
        f32x4 acc[8] = {};

        #pragma unroll
        for (int k0 = 0; k0 < KT; k0 += 64) {
            #pragma unroll
            for (int it = 0; it < 4; ++it) {
                int idx = it * 256 + tid;
                int brow = idx >> 3, bch = idx & 7;
                const bf16* gp = W + (size_t)(n0 + brow) * KT + k0 + ((bch ^ (brow & 7)) * 8);
                __builtin_amdgcn_global_load_lds((AS1 void*)gp, (AS3 void*)(Bs + idx * 8), 16, 0, 0);
            }
            bf16x8 av0, av1;
            if constexpr (KT != 128) {
                av0 = *(const bf16x8*)&ap[k0 + g * 8];
                av1 = *(const bf16x8*)&ap[k0 + 32 + g * 8];
            }
            __syncthreads();
            #pragma unroll
            for (int kk = 0; kk < 2; ++kk) {
                bf16x8 av;
                if constexpr (KT == 128) av = afrag[(k0 >> 5) + kk];
                else                     av = kk ? av1 : av0;
                #pragma unroll
                for (int j = 0; j < 8; ++j) {
                    int brow = j * 16 + li;
                    int bch = (kk * 4 + g) ^ (li & 7);
                    bf16x8 bv = *(const bf16x8*)&Bs[brow * 64 + bch * 8];
                    acc[j] = mfma16(av, bv, acc[j]);
                }
            }
            __syncthreads();
        }

        float bcol[8];
        #pragma unroll
        for (int j = 0; j < 8; ++j) bcol[j] = bias[n0 + j * 16 + li];

        const int row0 = m0 + w * 16 + g * 4;
        #pragma unroll
        for (int r = 0; r < 4; ++r) {
            int row = row0 + r;
            #pragma unroll
            for (int j = 0; j < 8; ++j) {
                size_t off = (size_t)row * N + n0 + j * 16 + li;
                float v = acc[j][r] + bcol[j];
                if constexpr (RES) {
                    if constexpr (RESBF) v += (float)((const bf16*)res)[off];
                    else                 v += ((const float*)res)[off];
                }
                if constexpr (GELU_) v = gelu_f(v);
                if constexpr (OUT_BF16) ((bf16*)outp)[off] = (bf16)v;
                else                    ((float*)outp)[off] = v;
            }
        }
    }
}

// ---------------------------------------------------------------------------
// Fused FFN, 8-wave version (r15, proven): counted-vmcnt pipeline, 16 phases,
// double-buffered Bs, depth 2, raw s_barrier + vmcnt(2).
// ---------------------------------------------------------------------------
__global__ __launch_bounds__(512) void ffn_fused(
    const bf16* __restrict__ A, const bf16* __restrict__ W1,
    const float* __restrict__ b1, const bf16* __restrict__ W2,
    const float* __restrict__ b2, const bf16* __restrict__ res,
    float* __restrict__ outp)
{
    __shared__ __align__(16) bf16 Bs[2][128 * 64];
    __shared__ __align__(16) bf16 hbuf[128 * 136];
    const int tid  = threadIdx.x;
    const int lane = tid & 63;
    const int w    = tid >> 6;          // 0..7
    const int li = lane & 15, g = lane >> 4;
    const int m0 = blockIdx.x * 128;
    const int arow = m0 + w * 16 + li;
    const bf16* ap = A + (size_t)arow * 128;

    bf16x8 axn[4];
    #pragma unroll
    for (int cc = 0; cc < 4; ++cc)
        axn[cc] = *(const bf16x8*)&ap[cc * 32 + g * 8];

    auto stageW1 = [&](int b, int t, int k0) {
        #pragma unroll
        for (int it = 0; it < 2; ++it) {
            int idx = it * 512 + tid;
            int brow = idx >> 3, bch = idx & 7;
            const bf16* gp = W1 + (size_t)(t * 128 + brow) * 128 + k0 + ((bch ^ (brow & 7)) * 8);
            __builtin_amdgcn_global_load_lds((AS1 void*)gp, (AS3 void*)(Bs[b] + idx * 8), 16, 0, 0);
        }
    };
    auto stageW2 = [&](int b, int t, int k0) {
        #pragma unroll
        for (int it = 0; it < 2; ++it) {
            int idx = it * 512 + tid;
            int brow = idx >> 3, bch = idx & 7;
            const bf16* gp = W2 + (size_t)brow * 512 + t * 128 + k0 + ((bch ^ (brow & 7)) * 8);
            __builtin_amdgcn_global_load_lds((AS1 void*)gp, (AS3 void*)(Bs[b] + idx * 8), 16, 0, 0);
        }
    };
    auto compute16 = [&](int b, bf16x8 av0, bf16x8 av1, f32x4* acc) {
        #pragma unroll
        for (int kk = 0; kk < 2; ++kk) {
            bf16x8 av = kk ? av1 : av0;
            #pragma unroll
            for (int j = 0; j < 8; ++j) {
                int brow = j * 16 + li;
                int bch = (kk * 4 + g) ^ (li & 7);
                bf16x8 bv = *(const bf16x8*)&Bs[b][brow * 64 + bch * 8];
                acc[j] = mfma16(av, bv, acc[j]);
            }
        }
    };

    f32x4 oacc[8] = {};

    stageW1(0, 0, 0);
    stageW1(1, 0, 64);

    #pragma unroll
    for (int t = 0; t < 4; ++t) {
        f32x4 hacc[8] = {};

        asm volatile("s_waitcnt vmcnt(2)" ::: "memory");
        __builtin_amdgcn_s_barrier();
        __builtin_amdgcn_sched_barrier(0);
        compute16(0, axn[0], axn[1], hacc);
        __builtin_amdgcn_sched_barrier(0);
        __builtin_amdgcn_s_barrier();
        stageW2(0, t, 0);

        asm volatile("s_waitcnt vmcnt(2)" ::: "memory");
        __builtin_amdgcn_s_barrier();
        __builtin_amdgcn_sched_barrier(0);
        compute16(1, axn[2], axn[3], hacc);
        __builtin_amdgcn_sched_barrier(0);
        __builtin_amdgcn_s_barrier();
        stageW2(1, t, 64);

        float b1c[8];
        #pragma unroll
        for (int j = 0; j < 8; ++j) b1c[j] = b1[t * 128 + j * 16 + li];
        #pragma unroll
        for (int r = 0; r < 4; ++r) {
            int lrow = w * 16 + g * 4 + r;
            #pragma unroll
            for (int j = 0; j < 8; ++j)
                hbuf[lrow * 136 + j * 16 + li] = (bf16)gelu_f(hacc[j][r] + b1c[j]);
        }
        bf16x8 ah[4];
        #pragma unroll
        for (int cc = 0; cc < 4; ++cc)
            ah[cc] = *(const bf16x8*)&hbuf[(w * 16 + li) * 136 + cc * 32 + g * 8];

        asm volatile("s_waitcnt vmcnt(2)" ::: "memory");
        __builtin_amdgcn_s_barrier();
        __builtin_amdgcn_sched_barrier(0);
        compute16(0, ah[0], ah[1], oacc);
        __builtin_amdgcn_sched_barrier(0);
        __builtin_amdgcn_s_barrier();
        if (t < 3) stageW1(0, t + 1, 0);

        if (t < 3) asm volatile("s_waitcnt vmcnt(2)" ::: "memory");
        else       asm volatile("s_waitcnt vmcnt(0)" ::: "memory");
        __builtin_amdgcn_s_barrier();
        __builtin_amdgcn_sched_barrier(0);
        compute16(1, ah[2], ah[3], oacc);
        __builtin_amdgcn_sched_barrier(0);
        __builtin_amdgcn_s_barrier();
        if (t < 3) stageW1(1, t + 1, 64);
    }

    float b2c[8];
    #pragma unroll
    for (int j = 0; j < 8; ++j) b2c[j] = b2[j * 16 + li];
    const int row0 = m0 + w * 16 + g * 4;
    #pragma unroll
    for (int r = 0; r < 4; ++r) {
        int row = row0 + r;
        #pragma unroll
        for (int j = 0; j < 8; ++j) {
            size_t off = (size_t)row * 128 + j * 16 + li;
            outp[off] = oacc[j][r] + b2c[j] + (float)res[off];
        }
    }
}

// ---------------------------------------------------------------------------
// Fused attention + out-projection + residual + LayerNorm. SINGLE-buffered
// cooperative K/V staging (22.5 KB LDS -> 7 blocks/CU, was 3): the extra
// barrier per chunk is hidden by the 2.3x block residency. Register prefetch
// (gload before compute) keeps HBM latency under the compute phase.
// MODE 0: heavy-first y order (qb = (3-y)*64); concurrent blocks stay
// same-qb/different-sequence (r16/r17 lesson: no cross-XCD K/V refetch).
// ---------------------------------------------------------------------------
template<int MODE, int RESBF>
__global__ __launch_bounds__(256) void attn_fused(
    const bf16* __restrict__ qkv, const bf16* __restrict__ Wo,
    const float* __restrict__ bo, const void* __restrict__ res,
    bf16* __restrict__ xc, bf16* __restrict__ xn,
    const float* __restrict__ lnw, const float* __restrict__ lnb)
{
    constexpr int S = (MODE == 0) ? 256 : 128;
    __shared__ __align__(16) char smem[20480 + 2048];
    float* red = (float*)(smem + 20480);
    const int tid = threadIdx.x;
    const int lane = tid & 63;
    const int w = tid >> 6;
    const int hi = lane >> 5;
    const int q31 = lane & 31;
    const int s = blockIdx.x;
    const int qb = (MODE == 0) ? ((3 - (int)blockIdx.y) * 64) : ((int)blockIdx.y * 64);

    const size_t base = (size_t)s * S * 384;
    const bf16* qp = qkv + base + w * 32;

    const float sc = 0.17677669529663687f;
    bf16x8 qA0, qA1, qB0, qB1;
    {
        bf16x8 r0 = *(const bf16x8*)&qp[(size_t)(qb + q31) * 384 + hi * 8];
        bf16x8 r1 = *(const bf16x8*)&qp[(size_t)(qb + q31) * 384 + 16 + hi * 8];
        bf16x8 r2 = *(const bf16x8*)&qp[(size_t)(qb + 32 + q31) * 384 + hi * 8];
        bf16x8 r3 = *(const bf16x8*)&qp[(size_t)(qb + 32 + q31) * 384 + 16 + hi * 8];
        #pragma unroll
        for (int e = 0; e < 8; ++e) {
            qA0[e] = (bf16)((float)r0[e] * sc);
            qA1[e] = (bf16)((float)r1[e] * sc);
            qB0[e] = (bf16)((float)r2[e] * sc);
            qB1[e] = (bf16)((float)r3[e] * sc);
        }
    }

    f32x16 OA = {}, OB = {};
    float lA = 0.f, lB = 0.f;

    int klo, khi;
    if constexpr (MODE == 0) { klo = 0; khi = qb + 64; }
    else {
        klo = (qb > 16 ? (qb - 16) : 0) & ~31;
        khi = (qb + 80 < S) ? (qb + 80) : S;
    }

    // cooperative staging: thread covers (row rw, row rw+16) x 16B segment seg
    const int seg = tid & 15, rw = tid >> 4;
    const char* qc = (const char*)qkv + base * 2;
    const int wdst = (seg >> 2) * 2560 + rw * 80 + (seg & 3) * 16;

    u32x4 rk0, rk1, rv0, rv1;
    auto gload = [&](int k0) {
        const char* r0 = qc + (size_t)(k0 + rw) * 768;
        const char* r1 = qc + (size_t)(k0 + rw + 16) * 768;
        rk0 = *(const u32x4*)(r0 + 256 + seg * 16);
        rk1 = *(const u32x4*)(r1 + 256 + seg * 16);
        rv0 = *(const u32x4*)(r0 + 512 + seg * 16);
        rv1 = *(const u32x4*)(r1 + 512 + seg * 16);
    };
    auto swrite = [&]() {
        *(u32x4*)(smem + wdst)                = rk0;
        *(u32x4*)(smem + wdst + 1280)         = rk1;
        *(u32x4*)(smem + 10240 + wdst)        = rv0;
        *(u32x4*)(smem + 10240 + wdst + 1280) = rv1;
    };

    gload(klo);
    swrite();
    __syncthreads();

    for (int k0 = klo; k0 < khi; k0 += 32) {
        bool notlast = (k0 + 32 < khi);
        if (notlast) gload(k0 + 32);

        const char* kb = smem + w * 2560 + q31 * 80 + hi * 16;
        bf16x8 kf0 = *(const bf16x8*)(kb);
        bf16x8 kf1 = *(const bf16x8*)(kb + 32);
        const bf16* vb = (const bf16*)(smem + 10240) + w * 1280 + hi * 320 + q31;
        bf16x8 vf1, vf2;
        #pragma unroll
        for (int e = 0; e < 8; ++e) {
            vf1[e] = vb[e * 40];
            vf2[e] = vb[640 + e * 40];
        }

        auto step = [&](f32x16& O, float& l, bf16x8 q0, bf16x8 q1,
                        int qrow, bool doMask) {
            f32x16 st = {};
            st = mfma32(kf0, q0, st);
            st = mfma32(kf1, q1, st);
            if (doMask) {
                #pragma unroll
                for (int r = 0; r < 16; ++r) {
                    int krow = k0 + (r & 3) + 8 * (r >> 2) + 4 * hi;
                    bool ok;
                    if constexpr (MODE == 0) ok = (krow <= qrow);
                    else { int d = krow - qrow; ok = (d <= 16 && d >= -16); }
                    st[r] = ok ? st[r] : -3.0e38f;
                }
            }
            float ps = 0.f;
            #pragma unroll
            for (int r = 0; r < 16; ++r) {
                float p = __expf(st[r]);     // static max 0: scores are O(1)
                st[r] = p;
                ps += p;
            }
            ps += __shfl_xor(ps, 32);
            l += ps;

            u32 c01 = pk2(st[0], st[1]),   c23 = pk2(st[2], st[3]);
            u32 c45 = pk2(st[4], st[5]),   c67 = pk2(st[6], st[7]);
            u32 c89 = pk2(st[8], st[9]),   cAB = pk2(st[10], st[11]);
            u32 cCD = pk2(st[12], st[13]), cEF = pk2(st[14], st[15]);
            u32 x01 = __shfl_xor((int)c01, 32), x23 = __shfl_xor((int)c23, 32);
            u32 x45 = __shfl_xor((int)c45, 32), x67 = __shfl_xor((int)c67, 32);
            u32 x89 = __shfl_xor((int)c89, 32), xAB = __shfl_xor((int)cAB, 32);
            u32 xCD = __shfl_xor((int)cCD, 32), xEF = __shfl_xor((int)cEF, 32);
            u32x4 b1w = hi ? u32x4{x45, x67, c45, c67} : u32x4{c01, c23, x01, x23};
            u32x4 b2w = hi ? u32x4{xCD, xEF, cCD, cEF} : u32x4{c89, cAB, x89, xAB};
            bf16x8 B1 = __builtin_bit_cast(bf16x8, b1w);
            bf16x8 B2 = __builtin_bit_cast(bf16x8, b2w);

            O = mfma32(vf1, B1, O);
            O = mfma32(vf2, B2, O);
        };

        bool actA, actB, dgA, dgB;
        if constexpr (MODE == 0) {
            actA = (k0 <= qb); actB = true;
            dgA = (k0 == qb);  dgB = (k0 == qb + 32);
        } else {
            actA = (k0 >= qb - 47) && (k0 <= qb + 47);
            actB = (k0 >= qb - 15) && (k0 <= qb + 79);
            dgA = true; dgB = true;
        }
        if (actA) step(OA, lA, qA0, qA1, qb + q31, dgA);
        if (actB) step(OB, lB, qB0, qB1, qb + 32 + q31, dgB);

        __syncthreads();               // all waves done READING smem
        if (notlast) {                 // block-uniform predicate
            swrite();
            __syncthreads();           // writes visible for next chunk
        }
    }

    // smem free now (post-compute barrier executed); stage O into o_lds
    bf16* o_lds = (bf16*)smem;
    float invA = 1.f / lA, invB = 1.f / lB;
    #pragma unroll
    for (int mb = 0; mb < 4; ++mb) {
        bf16x4 ovA, ovB;
        #pragma unroll
        for (int j = 0; j < 4; ++j) {
            ovA[j] = (bf16)(OA[mb * 4 + j] * invA);
            ovB[j] = (bf16)(OB[mb * 4 + j] * invB);
        }
        *(bf16x4*)&o_lds[q31 * 136 + w * 32 + mb * 8 + hi * 4] = ovA;
        *(bf16x4*)&o_lds[(32 + q31) * 136 + w * 32 + mb * 8 + hi * 4] = ovB;
    }
    __syncthreads();

    const int li = lane & 15, g = lane >> 4;
    bf16x8 af[4][4];
    #pragma unroll
    for (int mi = 0; mi < 4; ++mi)
        #pragma unroll
        for (int kk = 0; kk < 4; ++kk)
            af[mi][kk] = *(const bf16x8*)&o_lds[(mi * 16 + li) * 136 + kk * 32 + g * 8];

    f32x4 acc[4][2] = {};
    #pragma unroll
    for (int ni = 0; ni < 2; ++ni) {
        #pragma unroll
        for (int kk = 0; kk < 4; ++kk) {
            bf16x8 bv = *(const bf16x8*)&Wo[(size_t)(w * 32 + ni * 16 + li) * 128 + kk * 32 + g * 8];
            #pragma unroll
            for (int mi = 0; mi < 4; ++mi)
                acc[mi][ni] = mfma16(af[mi][kk], bv, acc[mi][ni]);
        }
    }

    float vals[4][2][4];
    #pragma unroll
    for (int mi = 0; mi < 4; ++mi) {
        #pragma unroll
        for (int r = 0; r < 4; ++r) {
            int lrl = mi * 16 + g * 4 + r;
            int grow = qb + lrl;
            size_t rrow;
            if constexpr (MODE == 0) {
                int b = s >> 7, f = s & 127;
                rrow = ((size_t)(b * 256 + grow)) * 128 + f;
            } else {
                int b = s >> 8, t = s & 255;
                rrow = (size_t)b * 32768 + (size_t)grow * 256 + t;
            }
            #pragma unroll
            for (int ni = 0; ni < 2; ++ni) {
                int col = w * 32 + ni * 16 + li;
                float v = acc[mi][ni][r] + bo[col];
                if constexpr (RESBF) v += (float)((const bf16*)res)[rrow * 128 + col];
                else                 v += ((const float*)res)[rrow * 128 + col];
                vals[mi][ni][r] = v;
            }
        }
    }
    #pragma unroll
    for (int mi = 0; mi < 4; ++mi) {
        #pragma unroll
        for (int r = 0; r < 4; ++r) {
            float sm = vals[mi][0][r] + vals[mi][1][r];
            float sq = vals[mi][0][r] * vals[mi][0][r] + vals[mi][1][r] * vals[mi][1][r];
            #pragma unroll
            for (int off = 1; off < 16; off <<= 1) {
                sm += __shfl_xor(sm, off);
                sq += __shfl_xor(sq, off);
            }
            if (li == 0) {
                red[(mi * 16 + g * 4 + r) * 8 + w * 2 + 0] = sm;
                red[(mi * 16 + g * 4 + r) * 8 + w * 2 + 1] = sq;
            }
        }
    }
    __syncthreads();
    #pragma unroll
    for (int mi = 0; mi < 4; ++mi) {
        #pragma unroll
        for (int r = 0; r < 4; ++r) {
            int mrow = mi * 16 + g * 4 + r;
            f32x4 p0 = *(const f32x4*)&red[mrow * 8 + 0];
            f32x4 p1 = *(const f32x4*)&red[mrow * 8 + 4];
            float smt = p0[0] + p0[2] + p1[0] + p1[2];
            float sqt = p0[1] + p0[3] + p1[1] + p1[3];
            float mu = smt * 0.0078125f;
            float rs = rsqrtf(sqt * 0.0078125f - mu * mu + 1e-5f);
            size_t woff = ((size_t)s * S + qb + mrow) * 128;
            #pragma unroll
            for (int ni = 0; ni < 2; ++ni) {
                int col = w * 32 + ni * 16 + li;
                float v = vals[mi][ni][r];
                xc[woff + col] = (bf16)v;
                xn[woff + col] = (bf16)((v - mu) * rs * lnw[col] + lnb[col]);
            }
        }
    }
}

// ---------------------------------------------------------------------------
extern "C" void kernel_launch(void* const* d_in, const int* in_sizes, int n_in,
                              void* d_out, int out_size, void* d_ws, size_t ws_size,
                              hipStream_t stream) {
    const float* x      = (const float*)d_in[0];
    const float* ln_t_w = (const float*)d_in[1];
    const float* ln_t_b = (const float*)d_in[2];
    const float* t_wi   = (const float*)d_in[3];
    const float* t_bi   = (const float*)d_in[4];
    const float* t_wo   = (const float*)d_in[5];
    const float* t_bo   = (const float*)d_in[6];
    const float* ln_f_w = (const float*)d_in[7];
    const float* ln_f_b = (const float*)d_in[8];
    const float* f_wi   = (const float*)d_in[9];
    const float* f_bi   = (const float*)d_in[10];
    const float* f_wo   = (const float*)d_in[11];
    const float* f_bo   = (const float*)d_in[12];
    const float* ln_n_w = (const float*)d_in[13];
    const float* ln_n_b = (const float*)d_in[14];
    const float* w1     = (const float*)d_in[15];
    const float* b1     = (const float*)d_in[16];
    const float* w2     = (const float*)d_in[17];
    const float* b2     = (const float*)d_in[18];

    char* ws = (char*)d_ws;
    bf16* wbf  = (bf16*)ws;                                      // 512 KB
    bf16* xn   = (bf16*)(ws + 524288);                           // 16 MB
    bf16* qkvh = (bf16*)(ws + 524288 + 16777216);                // 64 MB (qkv)
    bf16* xcA  = (bf16*)(ws + 524288 + 16777216 + 67108864 + 16777216);  // 16 MB
    bf16* xcB  = (bf16*)(ws + 524288 + 16777216 + 67108864 + 2 * 16777216); // 16 MB
    float* out = (float*)d_out;

    const bf16* twi_b = wbf + 0;
    const bf16* two_b = wbf + 49152;
    const bf16* fwi_b = wbf + 65536;
    const bf16* fwo_b = wbf + 114688;
    const bf16* w1_b  = wbf + 131072;
    const bf16* w2_b  = wbf + 196608;

    // 0) weights -> bf16
    cvt_w6<<<256, 256, 0, stream>>>(t_wi, t_wo, f_wi, f_wo, w1, w2, wbf);

    // 1) temporal: QKV (fused ln_t from f32 x, 3 N-tiles in-kernel, [B,F,T] rows),
    //    fused attn(causal, single-buffer coop K/V, heavy-first) -> xcA, xn
    gemm_rw<1, 0, 0, 0, 1, 0, 128, 3><<<1024, 256, 0, stream>>>(
        nullptr, twi_b, t_bi, nullptr, qkvh, x, ln_t_w, ln_t_b);
    attn_fused<0, 0><<<dim3(256, 4), 256, 0, stream>>>(
        qkvh, two_b, t_bo, x, xcA, xn, ln_f_w, ln_f_b);

    // 2) frequency: QKV (RMAP read), fused attn(band)+outproj+res+ln_n -> xcB, xn
    gemm_rw<1, 0, 0, 0, 0, 1, 128, 3><<<1024, 256, 0, stream>>>(
        xn, fwi_b, f_bi, nullptr, qkvh, nullptr, nullptr, nullptr);
    attn_fused<1, 1><<<dim3(512, 2), 256, 0, stream>>>(
        qkvh, fwo_b, f_bo, xcA, xcB, xn, ln_n_w, ln_n_b);

    // 3) FFN fused (8-wave, 128 rows/block): W1+GELU+W2 + res -> f32 d_out
    ffn_fused<<<512, 512, 0, stream>>>(xn, w1_b, b1, w2_b, b2, xcB, out);

    (void)in_sizes; (void)n_in; (void)out_size; (void)ws_size;
}

// Round 20
// 143.186 us; speedup vs baseline: 1.0161x; 1.0161x over previous
//
#include <hip/hip_runtime.h>
#include <math.h>

typedef __bf16 bf16;
typedef __bf16 bf16x8 __attribute__((ext_vector_type(8)));
typedef __bf16 bf16x4 __attribute__((ext_vector_type(4)));
typedef __bf16 bf16x2 __attribute__((ext_vector_type(2)));
typedef float f32x4 __attribute__((ext_vector_type(4)));
typedef float f32x2 __attribute__((ext_vector_type(2)));
typedef float f32x16 __attribute__((ext_vector_type(16)));
typedef unsigned int u32;
typedef unsigned int u32x4 __attribute__((ext_vector_type(4)));

#define AS1 __attribute__((address_space(1)))
#define AS3 __attribute__((address_space(3)))

static __device__ __forceinline__ f32x4 mfma16(bf16x8 a, bf16x8 b, f32x4 c) {
    return __builtin_amdgcn_mfma_f32_16x16x32_bf16(a, b, c, 0, 0, 0);
}
static __device__ __forceinline__ f32x16 mfma32(bf16x8 a, bf16x8 b, f32x16 c) {
    return __builtin_amdgcn_mfma_f32_32x32x16_bf16(a, b, c, 0, 0, 0);
}
static __device__ __forceinline__ u32 pk2(float a, float b) {
    bf16x2 v; v[0] = (bf16)a; v[1] = (bf16)b;
    return __builtin_bit_cast(u32, v);
}
// fast GELU (tanh form): max |err| vs exact-erf gelu ~5e-4.
static __device__ __forceinline__ float gelu_f(float x) {
    float u = 0.7978845608f * x * __builtin_fmaf(0.044715f, x * x, 1.0f);
    float e = __expf(2.0f * u);
    return x - x * __builtin_amdgcn_rcpf(e + 1.0f);
}

// ---------------------------------------------------------------------------
// Convert the six weight matrices f32 -> bf16 into one packed ws region.
// ---------------------------------------------------------------------------
__global__ __launch_bounds__(256) void cvt_w6(
    const float* __restrict__ s0, const float* __restrict__ s1,
    const float* __restrict__ s2, const float* __restrict__ s3,
    const float* __restrict__ s4, const float* __restrict__ s5,
    bf16* __restrict__ dst)
{
    int i = (blockIdx.x * 256 + threadIdx.x) * 4;
    const float* src; int off;
    if      (i <  49152) { src = s0; off = 0; }
    else if (i <  65536) { src = s1; off = 49152; }
    else if (i < 114688) { src = s2; off = 65536; }
    else if (i < 131072) { src = s3; off = 114688; }
    else if (i < 196608) { src = s4; off = 131072; }
    else                 { src = s5; off = 196608; }
    f32x4 v = *(const f32x4*)&src[i - off];
    bf16x4 b;
    b[0] = (bf16)v[0]; b[1] = (bf16)v[1]; b[2] = (bf16)v[2]; b[3] = (bf16)v[3];
    *(bf16x4*)&dst[i] = b;
}

// ---------------------------------------------------------------------------
// Row-wave GEMM (r13 version): out[M, NT*128] = epi(A @ W^T + bias (+res))
// Block = 64 rows, 4 waves; each wave owns 16 FULL rows. NT column tiles
// looped in-kernel so A (and the fused input-LN) is read/computed once.
// ---------------------------------------------------------------------------
template<int OUT_BF16, int RES, int RESBF, int GELU_, int LNA, int RMAP, int KT, int NT>
__global__ __launch_bounds__(256) void gemm_rw(
    const bf16* __restrict__ A, const bf16* __restrict__ W,
    const float* __restrict__ bias, const void* __restrict__ res,
    void* __restrict__ outp,
    const float* __restrict__ xf, const float* __restrict__ lnaw,
    const float* __restrict__ lnab)
{
    constexpr int N = NT * 128;
    __shared__ __align__(16) bf16 Bs[128 * 64];
    const int tid  = threadIdx.x;
    const int lane = tid & 63;
    const int w    = tid >> 6;
    const int li = lane & 15, g = lane >> 4;
    const int m0 = blockIdx.x * 64;
    const int arow = m0 + w * 16 + li;
    int srow = arow;
    if constexpr (RMAP) {
        int b = arow >> 15, t = (arow >> 7) & 255, f = arow & 127;
        srow = (b << 15) + (f << 8) + t;
    }
    const bf16* ap = A + (size_t)srow * KT;

    bf16x8 afrag[4];
    if constexpr (LNA) {
        // arow is in [B,F,T] order; source x row is [B,T,F]
        int b = arow >> 15, f = (arow >> 8) & 127, t = arow & 255;
        const float* xp = xf + (((size_t)b * 256 + t) * 128 + f) * 128;
        f32x4 cv[8];
        #pragma unroll
        for (int cc = 0; cc < 4; ++cc) {
            cv[2 * cc]     = *(const f32x4*)&xp[cc * 32 + g * 8];
            cv[2 * cc + 1] = *(const f32x4*)&xp[cc * 32 + g * 8 + 4];
        }
        float sm = 0.f, sq = 0.f;
        #pragma unroll
        for (int i = 0; i < 8; ++i)
            #pragma unroll
            for (int j = 0; j < 4; ++j) { float v = cv[i][j]; sm += v; sq += v * v; }
        sm += __shfl_xor(sm, 16); sm += __shfl_xor(sm, 32);
        sq += __shfl_xor(sq, 16); sq += __shfl_xor(sq, 32);
        float mu = sm * 0.0078125f;
        float rs = rsqrtf(sq * 0.0078125f - mu * mu + 1e-5f);
        #pragma unroll
        for (int cc = 0; cc < 4; ++cc) {
            f32x4 w0 = *(const f32x4*)&lnaw[cc * 32 + g * 8];
            f32x4 w1 = *(const f32x4*)&lnaw[cc * 32 + g * 8 + 4];
            f32x4 b0 = *(const f32x4*)&lnab[cc * 32 + g * 8];
            f32x4 b1 = *(const f32x4*)&lnab[cc * 32 + g * 8 + 4];
            #pragma unroll
            for (int j = 0; j < 4; ++j) {
                afrag[cc][j]     = (bf16)((cv[2 * cc][j]     - mu) * rs * w0[j] + b0[j]);
                afrag[cc][4 + j] = (bf16)((cv[2 * cc + 1][j] - mu) * rs * w1[j] + b1[j]);
            }
        }
    } else if constexpr (KT == 128) {
        #pragma unroll
        for (int cc = 0; cc < 4; ++cc)
            afrag[cc] = *(const bf16x8*)&ap[cc * 32 + g * 8];
    }

    #pragma unroll
    for (int t = 0; t < NT; ++t) {
        const int n0 = t * 128;
        f32x4 acc[8] = {};

        #pragma unroll
        for (int k0 = 0; k0 < KT; k0 += 64) {
            #pragma unroll
            for (int it = 0; it < 4; ++it) {
                int idx = it * 256 + tid;
                int brow = idx >> 3, bch = idx & 7;
                const bf16* gp = W + (size_t)(n0 + brow) * KT + k0 + ((bch ^ (brow & 7)) * 8);
                __builtin_amdgcn_global_load_lds((AS1 void*)gp, (AS3 void*)(Bs + idx * 8), 16, 0, 0);
            }
            bf16x8 av0, av1;
            if constexpr (KT != 128) {
                av0 = *(const bf16x8*)&ap[k0 + g * 8];
                av1 = *(const bf16x8*)&ap[k0 + 32 + g * 8];
            }
            __syncthreads();
            #pragma unroll
            for (int kk = 0; kk < 2; ++kk) {
                bf16x8 av;
                if constexpr (KT == 128) av = afrag[(k0 >> 5) + kk];
                else                     av = kk ? av1 : av0;
                #pragma unroll
                for (int j = 0; j < 8; ++j) {
                    int brow = j * 16 + li;
                    int bch = (kk * 4 + g) ^ (li & 7);
                    bf16x8 bv = *(const bf16x8*)&Bs[brow * 64 + bch * 8];
                    acc[j] = mfma16(av, bv, acc[j]);
                }
            }
            __syncthreads();
        }

        float bcol[8];
        #pragma unroll
        for (int j = 0; j < 8; ++j) bcol[j] = bias[n0 + j * 16 + li];

        const int row0 = m0 + w * 16 + g * 4;
        #pragma unroll
        for (int r = 0; r < 4; ++r) {
            int row = row0 + r;
            #pragma unroll
            for (int j = 0; j < 8; ++j) {
                size_t off = (size_t)row * N + n0 + j * 16 + li;
                float v = acc[j][r] + bcol[j];
                if constexpr (RES) {
                    if constexpr (RESBF) v += (float)((const bf16*)res)[off];
                    else                 v += ((const float*)res)[off];
                }
                if constexpr (GELU_) v = gelu_f(v);
                if constexpr (OUT_BF16) ((bf16*)outp)[off] = (bf16)v;
                else                    ((float*)outp)[off] = v;
            }
        }
    }
}

// ---------------------------------------------------------------------------
// Fused FFN, 8-wave version (r15, proven): counted-vmcnt pipeline, 16 phases,
// double-buffered Bs, depth 2, raw s_barrier + vmcnt(2).
// ---------------------------------------------------------------------------
__global__ __launch_bounds__(512) void ffn_fused(
    const bf16* __restrict__ A, const bf16* __restrict__ W1,
    const float* __restrict__ b1, const bf16* __restrict__ W2,
    const float* __restrict__ b2, const bf16* __restrict__ res,
    float* __restrict__ outp)
{
    __shared__ __align__(16) bf16 Bs[2][128 * 64];
    __shared__ __align__(16) bf16 hbuf[128 * 136];
    const int tid  = threadIdx.x;
    const int lane = tid & 63;
    const int w    = tid >> 6;          // 0..7
    const int li = lane & 15, g = lane >> 4;
    const int m0 = blockIdx.x * 128;
    const int arow = m0 + w * 16 + li;
    const bf16* ap = A + (size_t)arow * 128;

    bf16x8 axn[4];
    #pragma unroll
    for (int cc = 0; cc < 4; ++cc)
        axn[cc] = *(const bf16x8*)&ap[cc * 32 + g * 8];

    auto stageW1 = [&](int b, int t, int k0) {
        #pragma unroll
        for (int it = 0; it < 2; ++it) {
            int idx = it * 512 + tid;
            int brow = idx >> 3, bch = idx & 7;
            const bf16* gp = W1 + (size_t)(t * 128 + brow) * 128 + k0 + ((bch ^ (brow & 7)) * 8);
            __builtin_amdgcn_global_load_lds((AS1 void*)gp, (AS3 void*)(Bs[b] + idx * 8), 16, 0, 0);
        }
    };
    auto stageW2 = [&](int b, int t, int k0) {
        #pragma unroll
        for (int it = 0; it < 2; ++it) {
            int idx = it * 512 + tid;
            int brow = idx >> 3, bch = idx & 7;
            const bf16* gp = W2 + (size_t)brow * 512 + t * 128 + k0 + ((bch ^ (brow & 7)) * 8);
            __builtin_amdgcn_global_load_lds((AS1 void*)gp, (AS3 void*)(Bs[b] + idx * 8), 16, 0, 0);
        }
    };
    auto compute16 = [&](int b, bf16x8 av0, bf16x8 av1, f32x4* acc) {
        #pragma unroll
        for (int kk = 0; kk < 2; ++kk) {
            bf16x8 av = kk ? av1 : av0;
            #pragma unroll
            for (int j = 0; j < 8; ++j) {
                int brow = j * 16 + li;
                int bch = (kk * 4 + g) ^ (li & 7);
                bf16x8 bv = *(const bf16x8*)&Bs[b][brow * 64 + bch * 8];
                acc[j] = mfma16(av, bv, acc[j]);
            }
        }
    };

    f32x4 oacc[8] = {};

    stageW1(0, 0, 0);
    stageW1(1, 0, 64);

    #pragma unroll
    for (int t = 0; t < 4; ++t) {
        f32x4 hacc[8] = {};

        asm volatile("s_waitcnt vmcnt(2)" ::: "memory");
        __builtin_amdgcn_s_barrier();
        __builtin_amdgcn_sched_barrier(0);
        compute16(0, axn[0], axn[1], hacc);
        __builtin_amdgcn_sched_barrier(0);
        __builtin_amdgcn_s_barrier();
        stageW2(0, t, 0);

        asm volatile("s_waitcnt vmcnt(2)" ::: "memory");
        __builtin_amdgcn_s_barrier();
        __builtin_amdgcn_sched_barrier(0);
        compute16(1, axn[2], axn[3], hacc);
        __builtin_amdgcn_sched_barrier(0);
        __builtin_amdgcn_s_barrier();
        stageW2(1, t, 64);

        float b1c[8];
        #pragma unroll
        for (int j = 0; j < 8; ++j) b1c[j] = b1[t * 128 + j * 16 + li];
        #pragma unroll
        for (int r = 0; r < 4; ++r) {
            int lrow = w * 16 + g * 4 + r;
            #pragma unroll
            for (int j = 0; j < 8; ++j)
                hbuf[lrow * 136 + j * 16 + li] = (bf16)gelu_f(hacc[j][r] + b1c[j]);
        }
        bf16x8 ah[4];
        #pragma unroll
        for (int cc = 0; cc < 4; ++cc)
            ah[cc] = *(const bf16x8*)&hbuf[(w * 16 + li) * 136 + cc * 32 + g * 8];

        asm volatile("s_waitcnt vmcnt(2)" ::: "memory");
        __builtin_amdgcn_s_barrier();
        __builtin_amdgcn_sched_barrier(0);
        compute16(0, ah[0], ah[1], oacc);
        __builtin_amdgcn_sched_barrier(0);
        __builtin_amdgcn_s_barrier();
        if (t < 3) stageW1(0, t + 1, 0);

        if (t < 3) asm volatile("s_waitcnt vmcnt(2)" ::: "memory");
        else       asm volatile("s_waitcnt vmcnt(0)" ::: "memory");
        __builtin_amdgcn_s_barrier();
        __builtin_amdgcn_sched_barrier(0);
        compute16(1, ah[2], ah[3], oacc);
        __builtin_amdgcn_sched_barrier(0);
        __builtin_amdgcn_s_barrier();
        if (t < 3) stageW1(1, t + 1, 64);
    }

    float b2c[8];
    #pragma unroll
    for (int j = 0; j < 8; ++j) b2c[j] = b2[j * 16 + li];
    const int row0 = m0 + w * 16 + g * 4;
    #pragma unroll
    for (int r = 0; r < 4; ++r) {
        int row = row0 + r;
        #pragma unroll
        for (int j = 0; j < 8; ++j) {
            size_t off = (size_t)row * 128 + j * 16 + li;
            outp[off] = oacc[j][r] + b2c[j] + (float)res[off];
        }
    }
}

// ---------------------------------------------------------------------------
// Fused attention + out-projection + residual + LayerNorm, double-buffered
// cooperative K/V staging (r18 body). LDS squeezed to exactly 40960 B
// (red aliases KV buffer 1, used only after the loop) -> 4 blocks/CU
// (160 KiB / 40 KiB exactly), was 3 at 43008 B.
// MODE 0: heavy-first y order (qb = (3-y)*64); concurrent blocks stay
// same-qb/different-sequence (r16/r17 lesson: no cross-XCD K/V refetch).
// ---------------------------------------------------------------------------
template<int MODE, int RESBF>
__global__ __launch_bounds__(256) void attn_fused(
    const bf16* __restrict__ qkv, const bf16* __restrict__ Wo,
    const float* __restrict__ bo, const void* __restrict__ res,
    bf16* __restrict__ xc, bf16* __restrict__ xn,
    const float* __restrict__ lnw, const float* __restrict__ lnb)
{
    constexpr int S = (MODE == 0) ? 256 : 128;
    __shared__ __align__(16) char smem[2 * 20480];   // exactly 40 KiB
    float* red = (float*)(smem + 20480);             // aliases buffer 1 (epilogue only)
    const int tid = threadIdx.x;
    const int lane = tid & 63;
    const int w = tid >> 6;
    const int hi = lane >> 5;
    const int q31 = lane & 31;
    const int s = blockIdx.x;
    const int qb = (MODE == 0) ? ((3 - (int)blockIdx.y) * 64) : ((int)blockIdx.y * 64);

    const size_t base = (size_t)s * S * 384;
    const bf16* qp = qkv + base + w * 32;

    const float sc = 0.17677669529663687f;
    bf16x8 qA0, qA1, qB0, qB1;
    {
        bf16x8 r0 = *(const bf16x8*)&qp[(size_t)(qb + q31) * 384 + hi * 8];
        bf16x8 r1 = *(const bf16x8*)&qp[(size_t)(qb + q31) * 384 + 16 + hi * 8];
        bf16x8 r2 = *(const bf16x8*)&qp[(size_t)(qb + 32 + q31) * 384 + hi * 8];
        bf16x8 r3 = *(const bf16x8*)&qp[(size_t)(qb + 32 + q31) * 384 + 16 + hi * 8];
        #pragma unroll
        for (int e = 0; e < 8; ++e) {
            qA0[e] = (bf16)((float)r0[e] * sc);
            qA1[e] = (bf16)((float)r1[e] * sc);
            qB0[e] = (bf16)((float)r2[e] * sc);
            qB1[e] = (bf16)((float)r3[e] * sc);
        }
    }

    f32x16 OA = {}, OB = {};
    float lA = 0.f, lB = 0.f;

    int klo, khi;
    if constexpr (MODE == 0) { klo = 0; khi = qb + 64; }
    else {
        klo = (qb > 16 ? (qb - 16) : 0) & ~31;
        khi = (qb + 80 < S) ? (qb + 80) : S;
    }

    // cooperative staging: thread covers (row rw, row rw+16) x 16B segment seg
    const int seg = tid & 15, rw = tid >> 4;
    const char* qc = (const char*)qkv + base * 2;
    const int wdst = (seg >> 2) * 2560 + rw * 80 + (seg & 3) * 16;

    u32x4 rk0, rk1, rv0, rv1;
    auto gload = [&](int k0) {
        const char* r0 = qc + (size_t)(k0 + rw) * 768;
        const char* r1 = qc + (size_t)(k0 + rw + 16) * 768;
        rk0 = *(const u32x4*)(r0 + 256 + seg * 16);
        rk1 = *(const u32x4*)(r1 + 256 + seg * 16);
        rv0 = *(const u32x4*)(r0 + 512 + seg * 16);
        rv1 = *(const u32x4*)(r1 + 512 + seg * 16);
    };
    auto swrite = [&](char* buf) {
        *(u32x4*)(buf + wdst)                = rk0;
        *(u32x4*)(buf + wdst + 1280)         = rk1;
        *(u32x4*)(buf + 10240 + wdst)        = rv0;
        *(u32x4*)(buf + 10240 + wdst + 1280) = rv1;
    };

    gload(klo);
    swrite(smem);
    __syncthreads();
    int cur = 0;

    for (int k0 = klo; k0 < khi; k0 += 32) {
        bool notlast = (k0 + 32 < khi);
        if (notlast) gload(k0 + 32);

        char* buf = smem + cur * 20480;
        const char* kb = buf + w * 2560 + q31 * 80 + hi * 16;
        bf16x8 kf0 = *(const bf16x8*)(kb);
        bf16x8 kf1 = *(const bf16x8*)(kb + 32);
        const bf16* vb = (const bf16*)(buf + 10240) + w * 1280 + hi * 320 + q31;
        bf16x8 vf1, vf2;
        #pragma unroll
        for (int e = 0; e < 8; ++e) {
            vf1[e] = vb[e * 40];
            vf2[e] = vb[640 + e * 40];
        }

        auto step = [&](f32x16& O, float& l, bf16x8 q0, bf16x8 q1,
                        int qrow, bool doMask) {
            f32x16 st = {};
            st = mfma32(kf0, q0, st);
            st = mfma32(kf1, q1, st);
            if (doMask) {
                #pragma unroll
                for (int r = 0; r < 16; ++r) {
                    int krow = k0 + (r & 3) + 8 * (r >> 2) + 4 * hi;
                    bool ok;
                    if constexpr (MODE == 0) ok = (krow <= qrow);
                    else { int d = krow - qrow; ok = (d <= 16 && d >= -16); }
                    st[r] = ok ? st[r] : -3.0e38f;
                }
            }
            float ps = 0.f;
            #pragma unroll
            for (int r = 0; r < 16; ++r) {
                float p = __expf(st[r]);     // static max 0: scores are O(1)
                st[r] = p;
                ps += p;
            }
            ps += __shfl_xor(ps, 32);
            l += ps;

            u32 c01 = pk2(st[0], st[1]),   c23 = pk2(st[2], st[3]);
            u32 c45 = pk2(st[4], st[5]),   c67 = pk2(st[6], st[7]);
            u32 c89 = pk2(st[8], st[9]),   cAB = pk2(st[10], st[11]);
            u32 cCD = pk2(st[12], st[13]), cEF = pk2(st[14], st[15]);
            u32 x01 = __shfl_xor((int)c01, 32), x23 = __shfl_xor((int)c23, 32);
            u32 x45 = __shfl_xor((int)c45, 32), x67 = __shfl_xor((int)c67, 32);
            u32 x89 = __shfl_xor((int)c89, 32), xAB = __shfl_xor((int)cAB, 32);
            u32 xCD = __shfl_xor((int)cCD, 32), xEF = __shfl_xor((int)cEF, 32);
            u32x4 b1w = hi ? u32x4{x45, x67, c45, c67} : u32x4{c01, c23, x01, x23};
            u32x4 b2w = hi ? u32x4{xCD, xEF, cCD, cEF} : u32x4{c89, cAB, x89, xAB};
            bf16x8 B1 = __builtin_bit_cast(bf16x8, b1w);
            bf16x8 B2 = __builtin_bit_cast(bf16x8, b2w);

            O = mfma32(vf1, B1, O);
            O = mfma32(vf2, B2, O);
        };

        bool actA, actB, dgA, dgB;
        if constexpr (MODE == 0) {
            actA = (k0 <= qb); actB = true;
            dgA = (k0 == qb);  dgB = (k0 == qb + 32);
        } else {
            actA = (k0 >= qb - 47) && (k0 <= qb + 47);
            actB = (k0 >= qb - 15) && (k0 <= qb + 79);
            dgA = true; dgB = true;
        }
        if (actA) step(OA, lA, qA0, qA1, qb + q31, dgA);
        if (actB) step(OB, lB, qB0, qB1, qb + 32 + q31, dgB);

        if (notlast) swrite(smem + (cur ^ 1) * 20480);
        __syncthreads();
        cur ^= 1;
    }

    bf16* o_lds = (bf16*)smem;   // aliases buffer 0 (safe after final barrier)
    float invA = 1.f / lA, invB = 1.f / lB;
    #pragma unroll
    for (int mb = 0; mb < 4; ++mb) {
        bf16x4 ovA, ovB;
        #pragma unroll
        for (int j = 0; j < 4; ++j) {
            ovA[j] = (bf16)(OA[mb * 4 + j] * invA);
            ovB[j] = (bf16)(OB[mb * 4 + j] * invB);
        }
        *(bf16x4*)&o_lds[q31 * 136 + w * 32 + mb * 8 + hi * 4] = ovA;
        *(bf16x4*)&o_lds[(32 + q31) * 136 + w * 32 + mb * 8 + hi * 4] = ovB;
    }
    __syncthreads();

    const int li = lane & 15, g = lane >> 4;
    bf16x8 af[4][4];
    #pragma unroll
    for (int mi = 0; mi < 4; ++mi)
        #pragma unroll
        for (int kk = 0; kk < 4; ++kk)
            af[mi][kk] = *(const bf16x8*)&o_lds[(mi * 16 + li) * 136 + kk * 32 + g * 8];

    f32x4 acc[4][2] = {};
    #pragma unroll
    for (int ni = 0; ni < 2; ++ni) {
        #pragma unroll
        for (int kk = 0; kk < 4; ++kk) {
            bf16x8 bv = *(const bf16x8*)&Wo[(size_t)(w * 32 + ni * 16 + li) * 128 + kk * 32 + g * 8];
            #pragma unroll
            for (int mi = 0; mi < 4; ++mi)
                acc[mi][ni] = mfma16(af[mi][kk], bv, acc[mi][ni]);
        }
    }

    float vals[4][2][4];
    #pragma unroll
    for (int mi = 0; mi < 4; ++mi) {
        #pragma unroll
        for (int r = 0; r < 4; ++r) {
            int lrl = mi * 16 + g * 4 + r;
            int grow = qb + lrl;
            size_t rrow;
            if constexpr (MODE == 0) {
                int b = s >> 7, f = s & 127;
                rrow = ((size_t)(b * 256 + grow)) * 128 + f;
            } else {
                int b = s >> 8, t = s & 255;
                rrow = (size_t)b * 32768 + (size_t)grow * 256 + t;
            }
            #pragma unroll
            for (int ni = 0; ni < 2; ++ni) {
                int col = w * 32 + ni * 16 + li;
                float v = acc[mi][ni][r] + bo[col];
                if constexpr (RESBF) v += (float)((const bf16*)res)[rrow * 128 + col];
                else                 v += ((const float*)res)[rrow * 128 + col];
                vals[mi][ni][r] = v;
            }
        }
    }
    #pragma unroll
    for (int mi = 0; mi < 4; ++mi) {
        #pragma unroll
        for (int r = 0; r < 4; ++r) {
            float sm = vals[mi][0][r] + vals[mi][1][r];
            float sq = vals[mi][0][r] * vals[mi][0][r] + vals[mi][1][r] * vals[mi][1][r];
            #pragma unroll
            for (int off = 1; off < 16; off <<= 1) {
                sm += __shfl_xor(sm, off);
                sq += __shfl_xor(sq, off);
            }
            if (li == 0) {
                red[(mi * 16 + g * 4 + r) * 8 + w * 2 + 0] = sm;
                red[(mi * 16 + g * 4 + r) * 8 + w * 2 + 1] = sq;
            }
        }
    }
    __syncthreads();
    #pragma unroll
    for (int mi = 0; mi < 4; ++mi) {
        #pragma unroll
        for (int r = 0; r < 4; ++r) {
            int mrow = mi * 16 + g * 4 + r;
            f32x4 p0 = *(const f32x4*)&red[mrow * 8 + 0];
            f32x4 p1 = *(const f32x4*)&red[mrow * 8 + 4];
            float smt = p0[0] + p0[2] + p1[0] + p1[2];
            float sqt = p0[1] + p0[3] + p1[1] + p1[3];
            float mu = smt * 0.0078125f;
            float rs = rsqrtf(sqt * 0.0078125f - mu * mu + 1e-5f);
            size_t woff = ((size_t)s * S + qb + mrow) * 128;
            #pragma unroll
            for (int ni = 0; ni < 2; ++ni) {
                int col = w * 32 + ni * 16 + li;
                float v = vals[mi][ni][r];
                xc[woff + col] = (bf16)v;
                xn[woff + col] = (bf16)((v - mu) * rs * lnw[col] + lnb[col]);
            }
        }
    }
}

// ---------------------------------------------------------------------------
extern "C" void kernel_launch(void* const* d_in, const int* in_sizes, int n_in,
                              void* d_out, int out_size, void* d_ws, size_t ws_size,
                              hipStream_t stream) {
    const float* x      = (const float*)d_in[0];
    const float* ln_t_w = (const float*)d_in[1];
    const float* ln_t_b = (const float*)d_in[2];
    const float* t_wi   = (const float*)d_in[3];
    const float* t_bi   = (const float*)d_in[4];
    const float* t_wo   = (const float*)d_in[5];
    const float* t_bo   = (const float*)d_in[6];
    const float* ln_f_w = (const float*)d_in[7];
    const float* ln_f_b = (const float*)d_in[8];
    const float* f_wi   = (const float*)d_in[9];
    const float* f_bi   = (const float*)d_in[10];
    const float* f_wo   = (const float*)d_in[11];
    const float* f_bo   = (const float*)d_in[12];
    const float* ln_n_w = (const float*)d_in[13];
    const float* ln_n_b = (const float*)d_in[14];
    const float* w1     = (const float*)d_in[15];
    const float* b1     = (const float*)d_in[16];
    const float* w2     = (const float*)d_in[17];
    const float* b2     = (const float*)d_in[18];

    char* ws = (char*)d_ws;
    bf16* wbf  = (bf16*)ws;                                      // 512 KB
    bf16* xn   = (bf16*)(ws + 524288);                           // 16 MB
    bf16* qkvh = (bf16*)(ws + 524288 + 16777216);                // 64 MB (qkv)
    bf16* xcA  = (bf16*)(ws + 524288 + 16777216 + 67108864 + 16777216);  // 16 MB
    bf16* xcB  = (bf16*)(ws + 524288 + 16777216 + 67108864 + 2 * 16777216); // 16 MB
    float* out = (float*)d_out;

    const bf16* twi_b = wbf + 0;
    const bf16* two_b = wbf + 49152;
    const bf16* fwi_b = wbf + 65536;
    const bf16* fwo_b = wbf + 114688;
    const bf16* w1_b  = wbf + 131072;
    const bf16* w2_b  = wbf + 196608;

    // 0) weights -> bf16
    cvt_w6<<<256, 256, 0, stream>>>(t_wi, t_wo, f_wi, f_wo, w1, w2, wbf);

    // 1) temporal: QKV (fused ln_t from f32 x, 3 N-tiles in-kernel, [B,F,T] rows),
    //    fused attn(causal, dbuf coop K/V, heavy-first, 40 KiB LDS) -> xcA, xn
    gemm_rw<1, 0, 0, 0, 1, 0, 128, 3><<<1024, 256, 0, stream>>>(
        nullptr, twi_b, t_bi, nullptr, qkvh, x, ln_t_w, ln_t_b);
    attn_fused<0, 0><<<dim3(256, 4), 256, 0, stream>>>(
        qkvh, two_b, t_bo, x, xcA, xn, ln_f_w, ln_f_b);

    // 2) frequency: QKV (RMAP read), fused attn(band)+outproj+res+ln_n -> xcB, xn
    gemm_rw<1, 0, 0, 0, 0, 1, 128, 3><<<1024, 256, 0, stream>>>(
        xn, fwi_b, f_bi, nullptr, qkvh, nullptr, nullptr, nullptr);
    attn_fused<1, 1><<<dim3(512, 2), 256, 0, stream>>>(
        qkvh, fwo_b, f_bo, xcA, xcB, xn, ln_n_w, ln_n_b);

    // 3) FFN fused (8-wave, 128 rows/block): W1+GELU+W2 + res -> f32 d_out
    ffn_fused<<<512, 512, 0, stream>>>(xn, w1_b, b1, w2_b, b2, xcB, out);

    (void)in_sizes; (void)n_in; (void)out_size; (void)ws_size;
}

// Round 21
// 142.376 us; speedup vs baseline: 1.0219x; 1.0057x over previous
//
#include <hip/hip_runtime.h>
#include <math.h>

typedef __bf16 bf16;
typedef __bf16 bf16x8 __attribute__((ext_vector_type(8)));
typedef __bf16 bf16x4 __attribute__((ext_vector_type(4)));
typedef __bf16 bf16x2 __attribute__((ext_vector_type(2)));
typedef float f32x4 __attribute__((ext_vector_type(4)));
typedef float f32x2 __attribute__((ext_vector_type(2)));
typedef float f32x16 __attribute__((ext_vector_type(16)));
typedef unsigned int u32;
typedef unsigned int u32x4 __attribute__((ext_vector_type(4)));

#define AS1 __attribute__((address_space(1)))
#define AS3 __attribute__((address_space(3)))

static __device__ __forceinline__ f32x4 mfma16(bf16x8 a, bf16x8 b, f32x4 c) {
    return __builtin_amdgcn_mfma_f32_16x16x32_bf16(a, b, c, 0, 0, 0);
}
static __device__ __forceinline__ f32x16 mfma32(bf16x8 a, bf16x8 b, f32x16 c) {
    return __builtin_amdgcn_mfma_f32_32x32x16_bf16(a, b, c, 0, 0, 0);
}
static __device__ __forceinline__ u32 pk2(float a, float b) {
    bf16x2 v; v[0] = (bf16)a; v[1] = (bf16)b;
    return __builtin_bit_cast(u32, v);
}
// fast GELU (tanh form): max |err| vs exact-erf gelu ~5e-4.
static __device__ __forceinline__ float gelu_f(float x) {
    float u = 0.7978845608f * x * __builtin_fmaf(0.044715f, x * x, 1.0f);
    float e = __expf(2.0f * u);
    return x - x * __builtin_amdgcn_rcpf(e + 1.0f);
}

// ---------------------------------------------------------------------------
// Convert the six weight matrices f32 -> bf16 into one packed ws region.
// ---------------------------------------------------------------------------
__global__ __launch_bounds__(256) void cvt_w6(
    const float* __restrict__ s0, const float* __restrict__ s1,
    const float* __restrict__ s2, const float* __restrict__ s3,
    const float* __restrict__ s4, const float* __restrict__ s5,
    bf16* __restrict__ dst)
{
    int i = (blockIdx.x * 256 + threadIdx.x) * 4;
    const float* src; int off;
    if      (i <  49152) { src = s0; off = 0; }
    else if (i <  65536) { src = s1; off = 49152; }
    else if (i < 114688) { src = s2; off = 65536; }
    else if (i < 131072) { src = s3; off = 114688; }
    else if (i < 196608) { src = s4; off = 131072; }
    else                 { src = s5; off = 196608; }
    f32x4 v = *(const f32x4*)&src[i - off];
    bf16x4 b;
    b[0] = (bf16)v[0]; b[1] = (bf16)v[1]; b[2] = (bf16)v[2]; b[3] = (bf16)v[3];
    *(bf16x4*)&dst[i] = b;
}

// ---------------------------------------------------------------------------
// Row-wave GEMM (r13 version): out[M, NT*128] = epi(A @ W^T + bias (+res))
// Block = 64 rows, 4 waves; each wave owns 16 FULL rows. NT column tiles
// looped in-kernel so A (and the fused input-LN) is read/computed once.
// ---------------------------------------------------------------------------
template<int OUT_BF16, int RES, int RESBF, int GELU_, int LNA, int RMAP, int KT, int NT>
__global__ __launch_bounds__(256) void gemm_rw(
    const bf16* __restrict__ A, const bf16* __restrict__ W,
    const float* __restrict__ bias, const void* __restrict__ res,
    void* __restrict__ outp,
    const float* __restrict__ xf, const float* __restrict__ lnaw,
    const float* __restrict__ lnab)
{
    constexpr int N = NT * 128;
    __shared__ __align__(16) bf16 Bs[128 * 64];
    const int tid  = threadIdx.x;
    const int lane = tid & 63;
    const int w    = tid >> 6;
    const int li = lane & 15, g = lane >> 4;
    const int m0 = blockIdx.x * 64;
    const int arow = m0 + w * 16 + li;
    int srow = arow;
    if constexpr (RMAP) {
        int b = arow >> 15, t = (arow >> 7) & 255, f = arow & 127;
        srow = (b << 15) + (f << 8) + t;
    }
    const bf16* ap = A + (size_t)srow * KT;

    bf16x8 afrag[4];
    if constexpr (LNA) {
        // arow is in [B,F,T] order; source x row is [B,T,F]
        int b = arow >> 15, f = (arow >> 8) & 127, t = arow & 255;
        const float* xp = xf + (((size_t)b * 256 + t) * 128 + f) * 128;
        f32x4 cv[8];
        #pragma unroll
        for (int cc = 0; cc < 4; ++cc) {
            cv[2 * cc]     = *(const f32x4*)&xp[cc * 32 + g * 8];
            cv[2 * cc + 1] = *(const f32x4*)&xp[cc * 32 + g * 8 + 4];
        }
        float sm = 0.f, sq = 0.f;
        #pragma unroll
        for (int i = 0; i < 8; ++i)
            #pragma unroll
            for (int j = 0; j < 4; ++j) { float v = cv[i][j]; sm += v; sq += v * v; }
        sm += __shfl_xor(sm, 16); sm += __shfl_xor(sm, 32);
        sq += __shfl_xor(sq, 16); sq += __shfl_xor(sq, 32);
        float mu = sm * 0.0078125f;
        float rs = rsqrtf(sq * 0.0078125f - mu * mu + 1e-5f);
        #pragma unroll
        for (int cc = 0; cc < 4; ++cc) {
            f32x4 w0 = *(const f32x4*)&lnaw[cc * 32 + g * 8];
            f32x4 w1 = *(const f32x4*)&lnaw[cc * 32 + g * 8 + 4];
            f32x4 b0 = *(const f32x4*)&lnab[cc * 32 + g * 8];
            f32x4 b1 = *(const f32x4*)&lnab[cc * 32 + g * 8 + 4];
            #pragma unroll
            for (int j = 0; j < 4; ++j) {
                afrag[cc][j]     = (bf16)((cv[2 * cc][j]     - mu) * rs * w0[j] + b0[j]);
                afrag[cc][4 + j] = (bf16)((cv[2 * cc + 1][j] - mu) * rs * w1[j] + b1[j]);
            }
        }
    } else if constexpr (KT == 128) {
        #pragma unroll
        for (int cc = 0; cc < 4; ++cc)
            afrag[cc] = *(const bf16x8*)&ap[cc * 32 + g * 8];
    }

    #pragma unroll
    for (int t = 0; t < NT; ++t) {
        const int n0 = t * 128;
        f32x4 acc[8] = {};

        #pragma unroll
        for (int k0 = 0; k0 < KT; k0 += 64) {
            #pragma unroll
            for (int it = 0; it < 4; ++it) {
                int idx = it * 256 + tid;
                int brow = idx >> 3, bch = idx & 7;
                const bf16* gp = W + (size_t)(n0 + brow) * KT + k0 + ((bch ^ (brow & 7)) * 8);
                __builtin_amdgcn_global_load_lds((AS1 void*)gp, (AS3 void*)(Bs + idx * 8), 16, 0, 0);
            }
            bf16x8 av0, av1;
            if constexpr (KT != 128) {
                av0 = *(const bf16x8*)&ap[k0 + g * 8];
                av1 = *(const bf16x8*)&ap[k0 + 32 + g * 8];
            }
            __syncthreads();
            #pragma unroll
            for (int kk = 0; kk < 2; ++kk) {
                bf16x8 av;
                if constexpr (KT == 128) av = afrag[(k0 >> 5) + kk];
                else                     av = kk ? av1 : av0;
                #pragma unroll
                for (int j = 0; j < 8; ++j) {
                    int brow = j * 16 + li;
                    int bch = (kk * 4 + g) ^ (li & 7);
                    bf16x8 bv = *(const bf16x8*)&Bs[brow * 64 + bch * 8];
                    acc[j] = mfma16(av, bv, acc[j]);
                }
            }
            __syncthreads();
        }

        float bcol[8];
        #pragma unroll
        for (int j = 0; j < 8; ++j) bcol[j] = bias[n0 + j * 16 + li];

        const int row0 = m0 + w * 16 + g * 4;
        #pragma unroll
        for (int r = 0; r < 4; ++r) {
            int row = row0 + r;
            #pragma unroll
            for (int j = 0; j < 8; ++j) {
                size_t off = (size_t)row * N + n0 + j * 16 + li;
                float v = acc[j][r] + bcol[j];
                if constexpr (RES) {
                    if constexpr (RESBF) v += (float)((const bf16*)res)[off];
                    else                 v += ((const float*)res)[off];
                }
                if constexpr (GELU_) v = gelu_f(v);
                if constexpr (OUT_BF16) ((bf16*)outp)[off] = (bf16)v;
                else                    ((float*)outp)[off] = v;
            }
        }
    }
}

// ---------------------------------------------------------------------------
// Fused FFN, 8-wave version (r15, proven): counted-vmcnt pipeline, 16 phases,
// double-buffered Bs, depth 2, raw s_barrier + vmcnt(2).
// ---------------------------------------------------------------------------
__global__ __launch_bounds__(512) void ffn_fused(
    const bf16* __restrict__ A, const bf16* __restrict__ W1,
    const float* __restrict__ b1, const bf16* __restrict__ W2,
    const float* __restrict__ b2, const bf16* __restrict__ res,
    float* __restrict__ outp)
{
    __shared__ __align__(16) bf16 Bs[2][128 * 64];
    __shared__ __align__(16) bf16 hbuf[128 * 136];
    const int tid  = threadIdx.x;
    const int lane = tid & 63;
    const int w    = tid >> 6;          // 0..7
    const int li = lane & 15, g = lane >> 4;
    const int m0 = blockIdx.x * 128;
    const int arow = m0 + w * 16 + li;
    const bf16* ap = A + (size_t)arow * 128;

    bf16x8 axn[4];
    #pragma unroll
    for (int cc = 0; cc < 4; ++cc)
        axn[cc] = *(const bf16x8*)&ap[cc * 32 + g * 8];

    auto stageW1 = [&](int b, int t, int k0) {
        #pragma unroll
        for (int it = 0; it < 2; ++it) {
            int idx = it * 512 + tid;
            int brow = idx >> 3, bch = idx & 7;
            const bf16* gp = W1 + (size_t)(t * 128 + brow) * 128 + k0 + ((bch ^ (brow & 7)) * 8);
            __builtin_amdgcn_global_load_lds((AS1 void*)gp, (AS3 void*)(Bs[b] + idx * 8), 16, 0, 0);
        }
    };
    auto stageW2 = [&](int b, int t, int k0) {
        #pragma unroll
        for (int it = 0; it < 2; ++it) {
            int idx = it * 512 + tid;
            int brow = idx >> 3, bch = idx & 7;
            const bf16* gp = W2 + (size_t)brow * 512 + t * 128 + k0 + ((bch ^ (brow & 7)) * 8);
            __builtin_amdgcn_global_load_lds((AS1 void*)gp, (AS3 void*)(Bs[b] + idx * 8), 16, 0, 0);
        }
    };
    auto compute16 = [&](int b, bf16x8 av0, bf16x8 av1, f32x4* acc) {
        #pragma unroll
        for (int kk = 0; kk < 2; ++kk) {
            bf16x8 av = kk ? av1 : av0;
            #pragma unroll
            for (int j = 0; j < 8; ++j) {
                int brow = j * 16 + li;
                int bch = (kk * 4 + g) ^ (li & 7);
                bf16x8 bv = *(const bf16x8*)&Bs[b][brow * 64 + bch * 8];
                acc[j] = mfma16(av, bv, acc[j]);
            }
        }
    };

    f32x4 oacc[8] = {};

    stageW1(0, 0, 0);
    stageW1(1, 0, 64);

    #pragma unroll
    for (int t = 0; t < 4; ++t) {
        f32x4 hacc[8] = {};

        asm volatile("s_waitcnt vmcnt(2)" ::: "memory");
        __builtin_amdgcn_s_barrier();
        __builtin_amdgcn_sched_barrier(0);
        compute16(0, axn[0], axn[1], hacc);
        __builtin_amdgcn_sched_barrier(0);
        __builtin_amdgcn_s_barrier();
        stageW2(0, t, 0);

        asm volatile("s_waitcnt vmcnt(2)" ::: "memory");
        __builtin_amdgcn_s_barrier();
        __builtin_amdgcn_sched_barrier(0);
        compute16(1, axn[2], axn[3], hacc);
        __builtin_amdgcn_sched_barrier(0);
        __builtin_amdgcn_s_barrier();
        stageW2(1, t, 64);

        float b1c[8];
        #pragma unroll
        for (int j = 0; j < 8; ++j) b1c[j] = b1[t * 128 + j * 16 + li];
        #pragma unroll
        for (int r = 0; r < 4; ++r) {
            int lrow = w * 16 + g * 4 + r;
            #pragma unroll
            for (int j = 0; j < 8; ++j)
                hbuf[lrow * 136 + j * 16 + li] = (bf16)gelu_f(hacc[j][r] + b1c[j]);
        }
        bf16x8 ah[4];
        #pragma unroll
        for (int cc = 0; cc < 4; ++cc)
            ah[cc] = *(const bf16x8*)&hbuf[(w * 16 + li) * 136 + cc * 32 + g * 8];

        asm volatile("s_waitcnt vmcnt(2)" ::: "memory");
        __builtin_amdgcn_s_barrier();
        __builtin_amdgcn_sched_barrier(0);
        compute16(0, ah[0], ah[1], oacc);
        __builtin_amdgcn_sched_barrier(0);
        __builtin_amdgcn_s_barrier();
        if (t < 3) stageW1(0, t + 1, 0);

        if (t < 3) asm volatile("s_waitcnt vmcnt(2)" ::: "memory");
        else       asm volatile("s_waitcnt vmcnt(0)" ::: "memory");
        __builtin_amdgcn_s_barrier();
        __builtin_amdgcn_sched_barrier(0);
        compute16(1, ah[2], ah[3], oacc);
        __builtin_amdgcn_sched_barrier(0);
        __builtin_amdgcn_s_barrier();
        if (t < 3) stageW1(1, t + 1, 64);
    }

    float b2c[8];
    #pragma unroll
    for (int j = 0; j < 8; ++j) b2c[j] = b2[j * 16 + li];
    const int row0 = m0 + w * 16 + g * 4;
    #pragma unroll
    for (int r = 0; r < 4; ++r) {
        int row = row0 + r;
        #pragma unroll
        for (int j = 0; j < 8; ++j) {
            size_t off = (size_t)row * 128 + j * 16 + li;
            outp[off] = oacc[j][r] + b2c[j] + (float)res[off];
        }
    }
}

// ---------------------------------------------------------------------------
// Fused attention + out-projection + residual + LayerNorm, double-buffered
// cooperative K/V staging (r18/r20 body, 40 KiB LDS, 4 blocks/CU).
// This round: exp2-folded softmax (log2e folded into the Q pre-scale; bare
// v_exp_f32 per score, saving 32 v_mul/chunk on the dependency chain) and a
// pairwise tree-sum for the softmax denominator (4-level vs serial 16-add).
// MODE 0: heavy-first y order; concurrent blocks same-qb/different-sequence.
// ---------------------------------------------------------------------------
template<int MODE, int RESBF>
__global__ __launch_bounds__(256) void attn_fused(
    const bf16* __restrict__ qkv, const bf16* __restrict__ Wo,
    const float* __restrict__ bo, const void* __restrict__ res,
    bf16* __restrict__ xc, bf16* __restrict__ xn,
    const float* __restrict__ lnw, const float* __restrict__ lnb)
{
    constexpr int S = (MODE == 0) ? 256 : 128;
    __shared__ __align__(16) char smem[2 * 20480];   // exactly 40 KiB
    float* red = (float*)(smem + 20480);             // aliases buffer 1 (epilogue only)
    const int tid = threadIdx.x;
    const int lane = tid & 63;
    const int w = tid >> 6;
    const int hi = lane >> 5;
    const int q31 = lane & 31;
    const int s = blockIdx.x;
    const int qb = (MODE == 0) ? ((3 - (int)blockIdx.y) * 64) : ((int)blockIdx.y * 64);

    const size_t base = (size_t)s * S * 384;
    const bf16* qp = qkv + base + w * 32;

    // 1/sqrt(32) * log2(e): exp(s) == exp2(s * log2e), fold into Q pre-scale
    const float sc = 0.25503509f;
    bf16x8 qA0, qA1, qB0, qB1;
    {
        bf16x8 r0 = *(const bf16x8*)&qp[(size_t)(qb + q31) * 384 + hi * 8];
        bf16x8 r1 = *(const bf16x8*)&qp[(size_t)(qb + q31) * 384 + 16 + hi * 8];
        bf16x8 r2 = *(const bf16x8*)&qp[(size_t)(qb + 32 + q31) * 384 + hi * 8];
        bf16x8 r3 = *(const bf16x8*)&qp[(size_t)(qb + 32 + q31) * 384 + 16 + hi * 8];
        #pragma unroll
        for (int e = 0; e < 8; ++e) {
            qA0[e] = (bf16)((float)r0[e] * sc);
            qA1[e] = (bf16)((float)r1[e] * sc);
            qB0[e] = (bf16)((float)r2[e] * sc);
            qB1[e] = (bf16)((float)r3[e] * sc);
        }
    }

    f32x16 OA = {}, OB = {};
    float lA = 0.f, lB = 0.f;

    int klo, khi;
    if constexpr (MODE == 0) { klo = 0; khi = qb + 64; }
    else {
        klo = (qb > 16 ? (qb - 16) : 0) & ~31;
        khi = (qb + 80 < S) ? (qb + 80) : S;
    }

    // cooperative staging: thread covers (row rw, row rw+16) x 16B segment seg
    const int seg = tid & 15, rw = tid >> 4;
    const char* qc = (const char*)qkv + base * 2;
    const int wdst = (seg >> 2) * 2560 + rw * 80 + (seg & 3) * 16;

    u32x4 rk0, rk1, rv0, rv1;
    auto gload = [&](int k0) {
        const char* r0 = qc + (size_t)(k0 + rw) * 768;
        const char* r1 = qc + (size_t)(k0 + rw + 16) * 768;
        rk0 = *(const u32x4*)(r0 + 256 + seg * 16);
        rk1 = *(const u32x4*)(r1 + 256 + seg * 16);
        rv0 = *(const u32x4*)(r0 + 512 + seg * 16);
        rv1 = *(const u32x4*)(r1 + 512 + seg * 16);
    };
    auto swrite = [&](char* buf) {
        *(u32x4*)(buf + wdst)                = rk0;
        *(u32x4*)(buf + wdst + 1280)         = rk1;
        *(u32x4*)(buf + 10240 + wdst)        = rv0;
        *(u32x4*)(buf + 10240 + wdst + 1280) = rv1;
    };

    gload(klo);
    swrite(smem);
    __syncthreads();
    int cur = 0;

    for (int k0 = klo; k0 < khi; k0 += 32) {
        bool notlast = (k0 + 32 < khi);
        if (notlast) gload(k0 + 32);

        char* buf = smem + cur * 20480;
        const char* kb = buf + w * 2560 + q31 * 80 + hi * 16;
        bf16x8 kf0 = *(const bf16x8*)(kb);
        bf16x8 kf1 = *(const bf16x8*)(kb + 32);
        const bf16* vb = (const bf16*)(buf + 10240) + w * 1280 + hi * 320 + q31;
        bf16x8 vf1, vf2;
        #pragma unroll
        for (int e = 0; e < 8; ++e) {
            vf1[e] = vb[e * 40];
            vf2[e] = vb[640 + e * 40];
        }

        auto step = [&](f32x16& O, float& l, bf16x8 q0, bf16x8 q1,
                        int qrow, bool doMask) {
            f32x16 st = {};
            st = mfma32(kf0, q0, st);
            st = mfma32(kf1, q1, st);
            if (doMask) {
                #pragma unroll
                for (int r = 0; r < 16; ++r) {
                    int krow = k0 + (r & 3) + 8 * (r >> 2) + 4 * hi;
                    bool ok;
                    if constexpr (MODE == 0) ok = (krow <= qrow);
                    else { int d = krow - qrow; ok = (d <= 16 && d >= -16); }
                    st[r] = ok ? st[r] : -3.0e38f;
                }
            }
            // bare exp2 (log2e pre-folded into Q); pairwise tree denominator
            #pragma unroll
            for (int r = 0; r < 16; ++r)
                st[r] = __builtin_amdgcn_exp2f(st[r]);
            float a0 = st[0] + st[1],   a1 = st[2] + st[3];
            float a2 = st[4] + st[5],   a3 = st[6] + st[7];
            float a4 = st[8] + st[9],   a5 = st[10] + st[11];
            float a6 = st[12] + st[13], a7 = st[14] + st[15];
            float b0 = a0 + a1, b1 = a2 + a3, b2 = a4 + a5, b3 = a6 + a7;
            float ps = (b0 + b1) + (b2 + b3);
            ps += __shfl_xor(ps, 32);
            l += ps;

            u32 c01 = pk2(st[0], st[1]),   c23 = pk2(st[2], st[3]);
            u32 c45 = pk2(st[4], st[5]),   c67 = pk2(st[6], st[7]);
            u32 c89 = pk2(st[8], st[9]),   cAB = pk2(st[10], st[11]);
            u32 cCD = pk2(st[12], st[13]), cEF = pk2(st[14], st[15]);
            u32 x01 = __shfl_xor((int)c01, 32), x23 = __shfl_xor((int)c23, 32);
            u32 x45 = __shfl_xor((int)c45, 32), x67 = __shfl_xor((int)c67, 32);
            u32 x89 = __shfl_xor((int)c89, 32), xAB = __shfl_xor((int)cAB, 32);
            u32 xCD = __shfl_xor((int)cCD, 32), xEF = __shfl_xor((int)cEF, 32);
            u32x4 b1w = hi ? u32x4{x45, x67, c45, c67} : u32x4{c01, c23, x01, x23};
            u32x4 b2w = hi ? u32x4{xCD, xEF, cCD, cEF} : u32x4{c89, cAB, x89, xAB};
            bf16x8 B1 = __builtin_bit_cast(bf16x8, b1w);
            bf16x8 B2 = __builtin_bit_cast(bf16x8, b2w);

            O = mfma32(vf1, B1, O);
            O = mfma32(vf2, B2, O);
        };

        bool actA, actB, dgA, dgB;
        if constexpr (MODE == 0) {
            actA = (k0 <= qb); actB = true;
            dgA = (k0 == qb);  dgB = (k0 == qb + 32);
        } else {
            actA = (k0 >= qb - 47) && (k0 <= qb + 47);
            actB = (k0 >= qb - 15) && (k0 <= qb + 79);
            dgA = true; dgB = true;
        }
        if (actA) step(OA, lA, qA0, qA1, qb + q31, dgA);
        if (actB) step(OB, lB, qB0, qB1, qb + 32 + q31, dgB);

        if (notlast) swrite(smem + (cur ^ 1) * 20480);
        __syncthreads();
        cur ^= 1;
    }

    bf16* o_lds = (bf16*)smem;   // aliases buffer 0 (safe after final barrier)
    float invA = 1.f / lA, invB = 1.f / lB;
    #pragma unroll
    for (int mb = 0; mb < 4; ++mb) {
        bf16x4 ovA, ovB;
        #pragma unroll
        for (int j = 0; j < 4; ++j) {
            ovA[j] = (bf16)(OA[mb * 4 + j] * invA);
            ovB[j] = (bf16)(OB[mb * 4 + j] * invB);
        }
        *(bf16x4*)&o_lds[q31 * 136 + w * 32 + mb * 8 + hi * 4] = ovA;
        *(bf16x4*)&o_lds[(32 + q31) * 136 + w * 32 + mb * 8 + hi * 4] = ovB;
    }
    __syncthreads();

    const int li = lane & 15, g = lane >> 4;
    bf16x8 af[4][4];
    #pragma unroll
    for (int mi = 0; mi < 4; ++mi)
        #pragma unroll
        for (int kk = 0; kk < 4; ++kk)
            af[mi][kk] = *(const bf16x8*)&o_lds[(mi * 16 + li) * 136 + kk * 32 + g * 8];

    f32x4 acc[4][2] = {};
    #pragma unroll
    for (int ni = 0; ni < 2; ++ni) {
        #pragma unroll
        for (int kk = 0; kk < 4; ++kk) {
            bf16x8 bv = *(const bf16x8*)&Wo[(size_t)(w * 32 + ni * 16 + li) * 128 + kk * 32 + g * 8];
            #pragma unroll
            for (int mi = 0; mi < 4; ++mi)
                acc[mi][ni] = mfma16(af[mi][kk], bv, acc[mi][ni]);
        }
    }

    float vals[4][2][4];
    #pragma unroll
    for (int mi = 0; mi < 4; ++mi) {
        #pragma unroll
        for (int r = 0; r < 4; ++r) {
            int lrl = mi * 16 + g * 4 + r;
            int grow = qb + lrl;
            size_t rrow;
            if constexpr (MODE == 0) {
                int b = s >> 7, f = s & 127;
                rrow = ((size_t)(b * 256 + grow)) * 128 + f;
            } else {
                int b = s >> 8, t = s & 255;
                rrow = (size_t)b * 32768 + (size_t)grow * 256 + t;
            }
            #pragma unroll
            for (int ni = 0; ni < 2; ++ni) {
                int col = w * 32 + ni * 16 + li;
                float v = acc[mi][ni][r] + bo[col];
                if constexpr (RESBF) v += (float)((const bf16*)res)[rrow * 128 + col];
                else                 v += ((const float*)res)[rrow * 128 + col];
                vals[mi][ni][r] = v;
            }
        }
    }
    #pragma unroll
    for (int mi = 0; mi < 4; ++mi) {
        #pragma unroll
        for (int r = 0; r < 4; ++r) {
            float sm = vals[mi][0][r] + vals[mi][1][r];
            float sq = vals[mi][0][r] * vals[mi][0][r] + vals[mi][1][r] * vals[mi][1][r];
            #pragma unroll
            for (int off = 1; off < 16; off <<= 1) {
                sm += __shfl_xor(sm, off);
                sq += __shfl_xor(sq, off);
            }
            if (li == 0) {
                red[(mi * 16 + g * 4 + r) * 8 + w * 2 + 0] = sm;
                red[(mi * 16 + g * 4 + r) * 8 + w * 2 + 1] = sq;
            }
        }
    }
    __syncthreads();
    #pragma unroll
    for (int mi = 0; mi < 4; ++mi) {
        #pragma unroll
        for (int r = 0; r < 4; ++r) {
            int mrow = mi * 16 + g * 4 + r;
            f32x4 p0 = *(const f32x4*)&red[mrow * 8 + 0];
            f32x4 p1 = *(const f32x4*)&red[mrow * 8 + 4];
            float smt = p0[0] + p0[2] + p1[0] + p1[2];
            float sqt = p0[1] + p0[3] + p1[1] + p1[3];
            float mu = smt * 0.0078125f;
            float rs = rsqrtf(sqt * 0.0078125f - mu * mu + 1e-5f);
            size_t woff = ((size_t)s * S + qb + mrow) * 128;
            #pragma unroll
            for (int ni = 0; ni < 2; ++ni) {
                int col = w * 32 + ni * 16 + li;
                float v = vals[mi][ni][r];
                xc[woff + col] = (bf16)v;
                xn[woff + col] = (bf16)((v - mu) * rs * lnw[col] + lnb[col]);
            }
        }
    }
}

// ---------------------------------------------------------------------------
extern "C" void kernel_launch(void* const* d_in, const int* in_sizes, int n_in,
                              void* d_out, int out_size, void* d_ws, size_t ws_size,
                              hipStream_t stream) {
    const float* x      = (const float*)d_in[0];
    const float* ln_t_w = (const float*)d_in[1];
    const float* ln_t_b = (const float*)d_in[2];
    const float* t_wi   = (const float*)d_in[3];
    const float* t_bi   = (const float*)d_in[4];
    const float* t_wo   = (const float*)d_in[5];
    const float* t_bo   = (const float*)d_in[6];
    const float* ln_f_w = (const float*)d_in[7];
    const float* ln_f_b = (const float*)d_in[8];
    const float* f_wi   = (const float*)d_in[9];
    const float* f_bi   = (const float*)d_in[10];
    const float* f_wo   = (const float*)d_in[11];
    const float* f_bo   = (const float*)d_in[12];
    const float* ln_n_w = (const float*)d_in[13];
    const float* ln_n_b = (const float*)d_in[14];
    const float* w1     = (const float*)d_in[15];
    const float* b1     = (const float*)d_in[16];
    const float* w2     = (const float*)d_in[17];
    const float* b2     = (const float*)d_in[18];

    char* ws = (char*)d_ws;
    bf16* wbf  = (bf16*)ws;                                      // 512 KB
    bf16* xn   = (bf16*)(ws + 524288);                           // 16 MB
    bf16* qkvh = (bf16*)(ws + 524288 + 16777216);                // 64 MB (qkv)
    bf16* xcA  = (bf16*)(ws + 524288 + 16777216 + 67108864 + 16777216);  // 16 MB
    bf16* xcB  = (bf16*)(ws + 524288 + 16777216 + 67108864 + 2 * 16777216); // 16 MB
    float* out = (float*)d_out;

    const bf16* twi_b = wbf + 0;
    const bf16* two_b = wbf + 49152;
    const bf16* fwi_b = wbf + 65536;
    const bf16* fwo_b = wbf + 114688;
    const bf16* w1_b  = wbf + 131072;
    const bf16* w2_b  = wbf + 196608;

    // 0) weights -> bf16
    cvt_w6<<<256, 256, 0, stream>>>(t_wi, t_wo, f_wi, f_wo, w1, w2, wbf);

    // 1) temporal: QKV (fused ln_t from f32 x, 3 N-tiles in-kernel, [B,F,T] rows),
    //    fused attn(causal, dbuf coop K/V, heavy-first, exp2 softmax) -> xcA, xn
    gemm_rw<1, 0, 0, 0, 1, 0, 128, 3><<<1024, 256, 0, stream>>>(
        nullptr, twi_b, t_bi, nullptr, qkvh, x, ln_t_w, ln_t_b);
    attn_fused<0, 0><<<dim3(256, 4), 256, 0, stream>>>(
        qkvh, two_b, t_bo, x, xcA, xn, ln_f_w, ln_f_b);

    // 2) frequency: QKV (RMAP read), fused attn(band)+outproj+res+ln_n -> xcB, xn
    gemm_rw<1, 0, 0, 0, 0, 1, 128, 3><<<1024, 256, 0, stream>>>(
        xn, fwi_b, f_bi, nullptr, qkvh, nullptr, nullptr, nullptr);
    attn_fused<1, 1><<<dim3(512, 2), 256, 0, stream>>>(
        qkvh, fwo_b, f_bo, xcA, xcB, xn, ln_n_w, ln_n_b);

    // 3) FFN fused (8-wave, 128 rows/block): W1+GELU+W2 + res -> f32 d_out
    ffn_fused<<<512, 512, 0, stream>>>(xn, w1_b, b1, w2_b, b2, xcB, out);

    (void)in_sizes; (void)n_in; (void)out_size; (void)ws_size;
}